// Round 9
// baseline (349.104 us; speedup 1.0000x reference)
//
#include <hip/hip_runtime.h>
#include <math.h>

typedef __attribute__((ext_vector_type(8))) short bf16x8;
typedef __attribute__((ext_vector_type(4))) float f32x4;

__device__ __forceinline__ unsigned short f2bf(float x) {
    unsigned int u = __float_as_uint(x);
    u += 0x7fff + ((u >> 16) & 1);           // RNE
    return (unsigned short)(u >> 16);
}
__device__ __forceinline__ float bf2f(unsigned short b) {
    return __uint_as_float(((unsigned int)b) << 16);
}
__device__ __forceinline__ unsigned int cvtpk(float a, float b) {
    unsigned int r;
    asm("v_cvt_pk_bf16_f32 %0, %1, %2" : "=v"(r) : "v"(a), "v"(b));
    return r;
}
__device__ __forceinline__ float fast_tanh(float x) {
    float e = __expf(2.0f * x);
    return 1.0f - 2.0f / (e + 1.0f);
}
__device__ __forceinline__ f32x4 mfma16(bf16x8 a, bf16x8 b, f32x4 c) {
    return __builtin_amdgcn_mfma_f32_16x16x32_bf16(a, b, c, 0, 0, 0);
}
union bfu { unsigned int w[4]; bf16x8 v; };
__device__ __forceinline__ bf16x8 cvt8(float4 u, float4 v) {
    bfu x;
    x.w[0] = cvtpk(u.x, u.y); x.w[1] = cvtpk(u.z, u.w);
    x.w[2] = cvtpk(v.x, v.y); x.w[3] = cvtpk(v.z, v.w);
    return x.v;
}
__device__ __forceinline__ bf16x8 cvt8s(const float* s) {
    bfu x;
    x.w[0] = cvtpk(s[0], s[1]); x.w[1] = cvtpk(s[2], s[3]);
    x.w[2] = cvtpk(s[4], s[5]); x.w[3] = cvtpk(s[6], s[7]);
    return x.v;
}
// async global->LDS, 16B per lane; lds = wave-uniform base, g = per-lane src
__device__ __forceinline__ void async16(void* lds, const void* g) {
    __builtin_amdgcn_global_load_lds(
        (const __attribute__((address_space(1))) unsigned int*)g,
        (__attribute__((address_space(3))) unsigned int*)lds, 16, 0, 0);
}

#define SBAR0 __builtin_amdgcn_sched_barrier(0)

// ---------------------------------------------------------------------------
// Prep: weights -> frag-major bf16 (default k-map; R4 layout).
// ---------------------------------------------------------------------------
__global__ void prep_frag(const float* __restrict__ Wf, const float* __restrict__ W1,
                          const float* __restrict__ W2, const float* __restrict__ WL,
                          const float* __restrict__ WR,
                          unsigned short* __restrict__ WfF, unsigned short* __restrict__ W1F,
                          unsigned short* __restrict__ W2F, unsigned short* __restrict__ WLF,
                          unsigned short* __restrict__ WRF)
{
    int g = blockIdx.x * 256 + threadIdx.x;
    if (g >= 29696) return;
    int lane = g & 63, slot = g >> 6;
    int l15 = lane & 15, lkk = lane >> 4;

    unsigned short* dst;
    const float* W;
    int sl, NT, mode, Klim;
    if (slot < 16)       { dst = WfF; W = Wf; sl = slot;       NT = 8;  mode = 0; Klim = 39;  }
    else if (slot < 112) { dst = W1F; W = W1; sl = slot - 16;  NT = 8;  mode = 0; Klim = 384; }
    else if (slot < 144) { dst = W2F; W = W2; sl = slot - 112; NT = 8;  mode = 0; Klim = 128; }
    else if (slot < 304) { dst = WLF; W = WL; sl = slot - 144; NT = 16; mode = 1; Klim = 0;   }
    else                 { dst = WRF; W = WR; sl = slot - 304; NT = 16; mode = 1; Klim = 0;   }

    int ks = sl / NT;
    int n = (sl - ks * NT) * 16 + l15;
    int kb = ks * 32 + lkk * 8;
    unsigned short* o = dst + ((size_t)sl * 64 + lane) * 8;
    #pragma unroll
    for (int j = 0; j < 8; ++j) {
        int k = kb + j;
        float v;
        if (mode == 0) {
            v = (k < Klim) ? W[(size_t)k * 128 + n] : 0.0f;
        } else {
            if (k < 256)      v = W[(size_t)(39 + k) * 256 + n];
            else if (k < 295) v = W[(size_t)(k - 256) * 256 + n];
            else              v = 0.0f;
        }
        o[j] = f2bf(v);
    }
}

// ---------------------------------------------------------------------------
// Fused main kernel: Bresenham-interleaved atom / gather blocks.
//   atom path: deep-prefetch staged msg chunks (c0..c2 at kernel start),
//   counted vmcnt + raw s_barrier (no vmcnt(0) drains in steady state).
// ---------------------------------------------------------------------------
__global__ __launch_bounds__(256, 2) void fused_main(
    const float* __restrict__ af, const float* __restrict__ am,
    const unsigned short* __restrict__ WfF, const float* __restrict__ bfe,
    const unsigned short* __restrict__ W1F, const float* __restrict__ b1,
    const unsigned short* __restrict__ W2F, const float* __restrict__ b2,
    const unsigned short* __restrict__ WLF, const float* __restrict__ bL,
    const unsigned short* __restrict__ WRF, const float* __restrict__ bR,
    const int* __restrict__ seg, const int* __restrict__ leaf_idx,
    const int* __restrict__ ring_idx, const int* __restrict__ rseg,
    float* __restrict__ out_mol, int* __restrict__ counts,
    float* __restrict__ out_leaf, float* __restrict__ out_ring,
    int N, int NL, int NRE, int nLeafBlocks, int NG, int T)
{
    __shared__ alignas(16) unsigned char Ebuf[16384];    // E, later O
    __shared__ alignas(16) unsigned char Mbuf0[16384];   // c0, c3, then H
    __shared__ alignas(16) unsigned char Mbuf1[16384];   // c1
    __shared__ alignas(16) unsigned char Mbuf2[16384];   // c2
    __shared__ int sseg[64];

    const int t = threadIdx.x, lane = t & 63, w = t >> 6;
    const int lrow = lane & 15, lk = lane >> 4;

    const unsigned long long bid = blockIdx.x;
    const int g_before = (int)(bid * (unsigned long long)NG / (unsigned long long)T);
    const int g_after  = (int)((bid + 1ull) * (unsigned long long)NG / (unsigned long long)T);
    const bool is_gather = (g_after > g_before);

    if (!is_gather) {
        // ================= ATOM PATH =================
        const int ablk = (int)bid - g_before;
        const int r0 = ablk * 64;
        const int wr = w >> 1, wc = w & 1;

        auto stage_chunk = [&](unsigned char* buf, int cc) {
            #pragma unroll
            for (int it = 0; it < 4; ++it) {
                int i = t + it * 256;
                int r = i >> 4;
                int sgl = (i & 15) ^ (r & 15);
                const float* src = am + ((size_t)min(r0 + r, N - 1) << 8) + cc * 64 + sgl * 4;
                async16(buf + (size_t)(it * 256 + w * 64) * 16, src);
            }
        };
        auto compute_chunk = [&](const unsigned char* buf, int ksg0, f32x4 (&acc)[2][4]) {
            #pragma unroll
            for (int kk = 0; kk < 2; ++kk) {
                bf16x8 wb[4];
                const bf16x8* Wp = (const bf16x8*)W1F + ((size_t)(ksg0 + kk) * 8 + wc * 4) * 64 + lane;
                #pragma unroll
                for (int nt = 0; nt < 4; ++nt) wb[nt] = Wp[nt * 64];
                #pragma unroll
                for (int mt = 0; mt < 2; ++mt) {
                    int row = wr * 32 + mt * 16 + lrow;
                    int sg0 = kk * 8 + lk * 2;
                    float4 x0 = *(const float4*)(buf + row * 256 + ((sg0 ^ (row & 15)) << 4));
                    float4 x1 = *(const float4*)(buf + row * 256 + (((sg0 + 1) ^ (row & 15)) << 4));
                    bf16x8 a = cvt8(x0, x1);
                    #pragma unroll
                    for (int nt = 0; nt < 4; ++nt) acc[mt][nt] = mfma16(a, wb[nt], acc[mt][nt]);
                }
            }
        };
        auto tile_write = [&](unsigned char* buf, int row, int c, float v) {
            int byte = row * 256 + ((((c >> 3) ^ (row & 15))) << 4) + (c & 7) * 2;
            *(unsigned short*)(buf + byte) = f2bf(v);
        };

        // ---- preload EVERYTHING scalar (keeps VMEM clean around handoffs) ----
        float bfe_r[4], b1_r[4], b2_r[4];
        #pragma unroll
        for (int nt = 0; nt < 4; ++nt) {
            int c = wc * 64 + nt * 16 + lrow;
            bfe_r[nt] = bfe[c]; b1_r[nt] = b1[c]; b2_r[nt] = b2[c];
        }
        bf16x8 wf[2][4];
        #pragma unroll
        for (int ks = 0; ks < 2; ++ks) {
            const bf16x8* Wp = (const bf16x8*)WfF + ((size_t)ks * 8 + wc * 4) * 64 + lane;
            #pragma unroll
            for (int nt = 0; nt < 4; ++nt) wf[ks][nt] = Wp[nt * 64];
        }
        int rowg0 = min(r0 + wr * 32 + lrow, N - 1);
        int rowg1 = min(r0 + wr * 32 + 16 + lrow, N - 1);
        float av0[2][8], av1[2][8];
        #pragma unroll
        for (int ks = 0; ks < 2; ++ks)
            #pragma unroll
            for (int j = 0; j < 8; ++j) {
                int k = ks * 32 + lk * 8 + j;
                av0[ks][j] = (k < 39) ? af[(size_t)rowg0 * 39 + k] : 0.f;
                av1[ks][j] = (k < 39) ? af[(size_t)rowg1 * 39 + k] : 0.f;
            }
        if (t < 64) sseg[t] = (r0 + t < N) ? seg[r0 + t] : -1;

        // ---- deep prefetch: chunks 0..2 issued before any compute ----
        stage_chunk(Mbuf0, 0);
        stage_chunk(Mbuf1, 1);
        stage_chunk(Mbuf2, 2);
        SBAR0;

        // ---- phase 1: E = relu(af @ Wf + bf) -> Ebuf (no VMEM here) ----
        {
            f32x4 acc1[2][4] = {};
            #pragma unroll
            for (int ks = 0; ks < 2; ++ks) {
                bf16x8 a0 = cvt8s(av0[ks]);
                bf16x8 a1 = cvt8s(av1[ks]);
                #pragma unroll
                for (int nt = 0; nt < 4; ++nt) {
                    acc1[0][nt] = mfma16(a0, wf[ks][nt], acc1[0][nt]);
                    acc1[1][nt] = mfma16(a1, wf[ks][nt], acc1[1][nt]);
                }
            }
            #pragma unroll
            for (int nt = 0; nt < 4; ++nt) {
                int c = wc * 64 + nt * 16 + lrow;
                #pragma unroll
                for (int mt = 0; mt < 2; ++mt)
                    #pragma unroll
                    for (int rr = 0; rr < 4; ++rr) {
                        int row = wr * 32 + mt * 16 + lk * 4 + rr;
                        tile_write(Ebuf, row, c, fmaxf(acc1[mt][nt][rr] + bfe_r[nt], 0.f));
                    }
            }
        }
        // handoff A: c0 landed everywhere (c1,c2 stay in flight), E visible
        SBAR0;
        asm volatile("s_waitcnt vmcnt(8) lgkmcnt(0)" ::: "memory");
        __builtin_amdgcn_s_barrier();
        SBAR0;

        // ---- phase 2a: E-part + chunk c0 ----
        f32x4 acc2[2][4] = {};
        #pragma unroll
        for (int ks = 0; ks < 4; ++ks) {
            bf16x8 wb[4];
            const bf16x8* Wp = (const bf16x8*)W1F + ((size_t)ks * 8 + wc * 4) * 64 + lane;
            #pragma unroll
            for (int nt = 0; nt < 4; ++nt) wb[nt] = Wp[nt * 64];
            #pragma unroll
            for (int mt = 0; mt < 2; ++mt) {
                int row = wr * 32 + mt * 16 + lrow;
                int sg = ks * 4 + lk;
                bf16x8 a = *(const bf16x8*)(Ebuf + row * 256 + ((sg ^ (row & 15)) << 4));
                #pragma unroll
                for (int nt = 0; nt < 4; ++nt) acc2[mt][nt] = mfma16(a, wb[nt], acc2[mt][nt]);
            }
        }
        compute_chunk(Mbuf0, 4, acc2);

        // handoff B: c1 landed everywhere; B0 free for c3
        SBAR0;
        asm volatile("s_waitcnt vmcnt(4) lgkmcnt(0)" ::: "memory");
        __builtin_amdgcn_s_barrier();
        SBAR0;

        compute_chunk(Mbuf1, 6, acc2);   // c1
        stage_chunk(Mbuf0, 3);           // c3 -> B0 (last 4 VMEM issued)

        // handoff C: c2 landed everywhere (c3 stays in flight)
        SBAR0;
        asm volatile("s_waitcnt vmcnt(4) lgkmcnt(0)" ::: "memory");
        __builtin_amdgcn_s_barrier();
        SBAR0;

        compute_chunk(Mbuf2, 8, acc2);   // c2

        // handoff D: c3 landed everywhere
        SBAR0;
        asm volatile("s_waitcnt vmcnt(0) lgkmcnt(0)" ::: "memory");
        __builtin_amdgcn_s_barrier();
        SBAR0;

        compute_chunk(Mbuf0, 10, acc2);  // c3

        // ---- H epilogue -> Mbuf1 (all waves long past reading c1) ----
        #pragma unroll
        for (int nt = 0; nt < 4; ++nt) {
            int c = wc * 64 + nt * 16 + lrow;
            #pragma unroll
            for (int mt = 0; mt < 2; ++mt)
                #pragma unroll
                for (int rr = 0; rr < 4; ++rr) {
                    int row = wr * 32 + mt * 16 + lk * 4 + rr;
                    tile_write(Mbuf1, row, c, fmaxf(acc2[mt][nt][rr] + b1_r[nt], 0.f));
                }
        }
        // handoff E: H visible
        SBAR0;
        asm volatile("s_waitcnt lgkmcnt(0)" ::: "memory");
        __builtin_amdgcn_s_barrier();
        SBAR0;

        // ---- phase 3: O = tanh(H @ W2 + b2) -> Ebuf overlay ----
        {
            f32x4 acc3[2][4] = {};
            #pragma unroll
            for (int ks = 0; ks < 4; ++ks) {
                bf16x8 wb[4];
                const bf16x8* Wp = (const bf16x8*)W2F + ((size_t)ks * 8 + wc * 4) * 64 + lane;
                #pragma unroll
                for (int nt = 0; nt < 4; ++nt) wb[nt] = Wp[nt * 64];
                #pragma unroll
                for (int mt = 0; mt < 2; ++mt) {
                    int row = wr * 32 + mt * 16 + lrow;
                    int sg = ks * 4 + lk;
                    bf16x8 a = *(const bf16x8*)(Mbuf1 + row * 256 + ((sg ^ (row & 15)) << 4));
                    #pragma unroll
                    for (int nt = 0; nt < 4; ++nt) acc3[mt][nt] = mfma16(a, wb[nt], acc3[mt][nt]);
                }
            }
            #pragma unroll
            for (int nt = 0; nt < 4; ++nt) {
                int c = wc * 64 + nt * 16 + lrow;
                #pragma unroll
                for (int mt = 0; mt < 2; ++mt)
                    #pragma unroll
                    for (int rr = 0; rr < 4; ++rr) {
                        int row = wr * 32 + mt * 16 + lk * 4 + rr;
                        tile_write(Ebuf, row, c, fast_tanh(acc3[mt][nt][rr] + b2_r[nt]));
                    }
            }
        }
        asm volatile("s_waitcnt lgkmcnt(0)" ::: "memory");
        SBAR0;

        // ---- pooling: wave owns its own 32-row x 64-col quadrant of O ----
        {
            const int c = wc * 64 + lane;
            int cur = -1, runlen = 0;
            float s = 0.f, m = 0.f;
            #pragma unroll 1
            for (int a2 = 0; a2 < 32; ++a2) {
                int arow = wr * 32 + a2;
                int sg = sseg[arow];
                if (sg < 0) break;
                int byte = arow * 256 + ((((c >> 3) ^ (arow & 15))) << 4) + (c & 7) * 2;
                float v = bf2f(*(const unsigned short*)(Ebuf + byte));
                if (sg != cur) {
                    if (cur >= 0) {
                        atomicAdd(&out_mol[(size_t)cur * 256 + c], s);
                        atomicMax((unsigned int*)&out_mol[(size_t)cur * 256 + 128 + c],
                                  __float_as_uint(m + 2.0f));
                        if (wc == 0 && lane == 0) atomicAdd(&counts[cur], runlen);
                    }
                    cur = sg; s = v; m = v; runlen = 1;
                } else {
                    s += v; m = fmaxf(m, v); ++runlen;
                }
            }
            if (cur >= 0) {
                atomicAdd(&out_mol[(size_t)cur * 256 + c], s);
                atomicMax((unsigned int*)&out_mol[(size_t)cur * 256 + 128 + c],
                          __float_as_uint(m + 2.0f));
                if (wc == 0 && lane == 0) atomicAdd(&counts[cur], runlen);
            }
        }
        return;
    }

    // ================= GATHER PATH (leaf / ring) =================
    {
        const int gblk = g_before;
        const bool ring = gblk >= nLeafBlocks;
        const unsigned short* WF = ring ? WRF : WLF;
        const float* bv = ring ? bR : bL;
        const int* idx = ring ? ring_idx : leaf_idx;
        const int NROWS = ring ? NRE : NL;
        const int blk = ring ? gblk - nLeafBlocks : gblk;

        const int r0 = blk * 64 + (w & 1) * 32;
        const int colblk = w >> 1;
        const int i0 = idx[min(r0 + lrow, NROWS - 1)];
        const int i1 = idx[min(r0 + 16 + lrow, NROWS - 1)];

        f32x4 acc[2][8] = {};
        #pragma unroll
        for (int ks = 0; ks < 8; ++ks) {
            int k0 = ks * 32 + lk * 8;
            const float* p0 = am + ((size_t)i0 << 8) + k0;
            const float* p1 = am + ((size_t)i1 << 8) + k0;
            bf16x8 a0 = cvt8(*(const float4*)p0, *(const float4*)(p0 + 4));
            bf16x8 a1 = cvt8(*(const float4*)p1, *(const float4*)(p1 + 4));
            const bf16x8* B = (const bf16x8*)WF + (ks * 16 + colblk * 8) * 64 + lane;
            #pragma unroll
            for (int nt = 0; nt < 8; ++nt) {
                bf16x8 b = B[nt * 64];
                acc[0][nt] = mfma16(a0, b, acc[0][nt]);
                acc[1][nt] = mfma16(a1, b, acc[1][nt]);
            }
        }
        #pragma unroll
        for (int ks = 8; ks < 10; ++ks) {
            bf16x8 a0, a1;
            #pragma unroll
            for (int j = 0; j < 8; ++j) {
                int k = ks * 32 + lk * 8 + j - 256;
                float v0 = (k < 39) ? af[(size_t)i0 * 39 + k] : 0.0f;
                float v1 = (k < 39) ? af[(size_t)i1 * 39 + k] : 0.0f;
                a0[j] = (short)f2bf(v0); a1[j] = (short)f2bf(v1);
            }
            const bf16x8* B = (const bf16x8*)WF + (ks * 16 + colblk * 8) * 64 + lane;
            #pragma unroll
            for (int nt = 0; nt < 8; ++nt) {
                bf16x8 b = B[nt * 64];
                acc[0][nt] = mfma16(a0, b, acc[0][nt]);
                acc[1][nt] = mfma16(a1, b, acc[1][nt]);
            }
        }

        if (!ring) {
            #pragma unroll
            for (int nt = 0; nt < 8; ++nt) {
                int c = colblk * 128 + nt * 16 + lrow;
                float bias = bv[c];
                #pragma unroll
                for (int mt = 0; mt < 2; ++mt) {
                    #pragma unroll
                    for (int r = 0; r < 4; ++r) {
                        int row = r0 + mt * 16 + lk * 4 + r;
                        if (row < NROWS)
                            out_leaf[(size_t)row * 256 + c] = fast_tanh(acc[mt][nt][r] + bias);
                    }
                }
            }
        } else {
            int sg[2][4];
            #pragma unroll
            for (int mt = 0; mt < 2; ++mt)
                #pragma unroll
                for (int r = 0; r < 4; ++r) {
                    int rr = r0 + mt * 16 + lk * 4 + r;
                    sg[mt][r] = (rr < NROWS) ? rseg[rr] : -1;
                }
            #pragma unroll
            for (int nt = 0; nt < 8; ++nt) {
                int c = colblk * 128 + nt * 16 + lrow;
                float bias = bv[c];
                #pragma unroll
                for (int mt = 0; mt < 2; ++mt) {
                    int cur = -1; float accv = 0.0f;
                    #pragma unroll
                    for (int r = 0; r < 4; ++r) {
                        float v = fast_tanh(acc[mt][nt][r] + bias);
                        int s = sg[mt][r];
                        if (s != cur) {
                            if (cur >= 0) atomicAdd(&out_ring[(size_t)cur * 256 + c], accv);
                            cur = s; accv = v;
                        } else accv += v;
                    }
                    if (cur >= 0) atomicAdd(&out_ring[(size_t)cur * 256 + c], accv);
                }
            }
        }
    }
}

// ---------------------------------------------------------------------------
// Finalize molecule embedding in-place: avg = sum/count, max decode
// ---------------------------------------------------------------------------
__global__ void finalize_kernel(float* __restrict__ out, const int* __restrict__ counts, int M)
{
    int tid = blockIdx.x * blockDim.x + threadIdx.x;
    if (tid >= M * 128) return;
    int m = tid >> 7, c = tid & 127;
    int cnt = counts[m];
    float denom = (cnt > 0) ? (float)cnt : 1.0f;
    float s  = out[(size_t)m * 256 + c];
    float mr = out[(size_t)m * 256 + 128 + c];
    out[(size_t)m * 256 + c] = s / denom;
    out[(size_t)m * 256 + 128 + c] = (cnt > 0) ? (mr - 2.0f) : 0.0f;
}

extern "C" void kernel_launch(void* const* d_in, const int* in_sizes, int n_in,
                              void* d_out, int out_size, void* d_ws, size_t ws_size,
                              hipStream_t stream) {
    const float* af = (const float*)d_in[0];
    const float* am = (const float*)d_in[1];
    const float* Wf = (const float*)d_in[2];
    const float* bfe = (const float*)d_in[3];
    const float* W1 = (const float*)d_in[4];
    const float* b1 = (const float*)d_in[5];
    const float* W2 = (const float*)d_in[6];
    const float* b2 = (const float*)d_in[7];
    const float* WL = (const float*)d_in[8];
    const float* bL = (const float*)d_in[9];
    const float* WR = (const float*)d_in[10];
    const float* bR = (const float*)d_in[11];
    const int* seg      = (const int*)d_in[12];
    const int* leaf_idx = (const int*)d_in[13];
    const int* ring_idx = (const int*)d_in[14];
    const int* ring_seg = (const int*)d_in[15];

    const int N   = in_sizes[0] / 39;   // 300000
    const int NL  = in_sizes[13];       // 50000
    const int NRE = in_sizes[14];       // 120000
    const int M   = 10000;
    const int NR  = 20000;

    float* out = (float*)d_out;
    float* out_mol  = out;
    float* out_leaf = out + (size_t)M * 256;
    float* out_ring = out + (size_t)M * 256 + (size_t)NL * 256;

    // ws layout (16B-aligned offsets)
    int* counts = (int*)d_ws;                                       // 40 KB
    unsigned short* WfF = (unsigned short*)((char*)d_ws + 40960);   // 16 KB
    unsigned short* W1F = (unsigned short*)((char*)d_ws + 57344);   // 96 KB
    unsigned short* W2F = (unsigned short*)((char*)d_ws + 155648);  // 32 KB
    unsigned short* WLF = (unsigned short*)((char*)d_ws + 188416);  // 160 KB
    unsigned short* WRF = (unsigned short*)((char*)d_ws + 352256);  // 160 KB

    hipMemsetAsync(out_mol, 0, (size_t)M * 256 * sizeof(float), stream);
    hipMemsetAsync(out_ring, 0, (size_t)NR * 256 * sizeof(float), stream);
    hipMemsetAsync(counts, 0, (size_t)M * sizeof(int), stream);

    prep_frag<<<(29696 + 255) / 256, 256, 0, stream>>>(
        Wf, W1, W2, WL, WR, WfF, W1F, W2F, WLF, WRF);

    const int NA = (N + 63) / 64;                 // atom blocks
    const int nLeafBlocks = (NL + 63) / 64;
    const int nRingBlocks = (NRE + 63) / 64;
    const int NG = nLeafBlocks + nRingBlocks;     // gather blocks
    const int T  = NA + NG;

    fused_main<<<T, 256, 0, stream>>>(
        af, am, WfF, bfe, W1F, b1, W2F, b2, WLF, bL, WRF, bR,
        seg, leaf_idx, ring_idx, ring_seg,
        out_mol, counts, out_leaf, out_ring,
        N, NL, NRE, nLeafBlocks, NG, T);

    finalize_kernel<<<(M * 128 + 255) / 256, 256, 0, stream>>>(out_mol, counts, M);
}

// Round 10
// 304.690 us; speedup vs baseline: 1.1458x; 1.1458x over previous
//
#include <hip/hip_runtime.h>
#include <math.h>

typedef __attribute__((ext_vector_type(8))) short bf16x8;
typedef __attribute__((ext_vector_type(4))) float f32x4;

__device__ __forceinline__ unsigned short f2bf(float x) {
    unsigned int u = __float_as_uint(x);
    u += 0x7fff + ((u >> 16) & 1);           // RNE
    return (unsigned short)(u >> 16);
}
__device__ __forceinline__ float bf2f(unsigned short b) {
    return __uint_as_float(((unsigned int)b) << 16);
}
__device__ __forceinline__ unsigned int cvtpk(float a, float b) {
    unsigned int r;
    asm("v_cvt_pk_bf16_f32 %0, %1, %2" : "=v"(r) : "v"(a), "v"(b));
    return r;
}
__device__ __forceinline__ float fast_tanh(float x) {
    float e = __expf(2.0f * x);
    return 1.0f - 2.0f / (e + 1.0f);
}
__device__ __forceinline__ f32x4 mfma16(bf16x8 a, bf16x8 b, f32x4 c) {
    return __builtin_amdgcn_mfma_f32_16x16x32_bf16(a, b, c, 0, 0, 0);
}
union bfu { unsigned int w[4]; bf16x8 v; };
__device__ __forceinline__ bf16x8 cvt8(float4 u, float4 v) {
    bfu x;
    x.w[0] = cvtpk(u.x, u.y); x.w[1] = cvtpk(u.z, u.w);
    x.w[2] = cvtpk(v.x, v.y); x.w[3] = cvtpk(v.z, v.w);
    return x.v;
}
__device__ __forceinline__ bf16x8 cvt8s(const float* s) {
    bfu x;
    x.w[0] = cvtpk(s[0], s[1]); x.w[1] = cvtpk(s[2], s[3]);
    x.w[2] = cvtpk(s[4], s[5]); x.w[3] = cvtpk(s[6], s[7]);
    return x.v;
}
__device__ __forceinline__ void async16(void* lds, const void* g) {
    __builtin_amdgcn_global_load_lds(
        (const __attribute__((address_space(1))) unsigned int*)g,
        (__attribute__((address_space(3))) unsigned int*)lds, 16, 0, 0);
}

#define SBAR0 __builtin_amdgcn_sched_barrier(0)
// barrier with counted vmcnt: keeps the newest VM in-flight loads alive
#define BARX(vm) do { SBAR0; \
    asm volatile("s_waitcnt vmcnt(" #vm ") lgkmcnt(0)" ::: "memory"); \
    __builtin_amdgcn_s_barrier(); SBAR0; } while (0)

// ---------------------------------------------------------------------------
// Prep: weights -> frag-major bf16 (default k-map; R4 layout).
// ---------------------------------------------------------------------------
__global__ void prep_frag(const float* __restrict__ Wf, const float* __restrict__ W1,
                          const float* __restrict__ W2, const float* __restrict__ WL,
                          const float* __restrict__ WR,
                          unsigned short* __restrict__ WfF, unsigned short* __restrict__ W1F,
                          unsigned short* __restrict__ W2F, unsigned short* __restrict__ WLF,
                          unsigned short* __restrict__ WRF)
{
    int g = blockIdx.x * 256 + threadIdx.x;
    if (g >= 29696) return;
    int lane = g & 63, slot = g >> 6;
    int l15 = lane & 15, lkk = lane >> 4;

    unsigned short* dst;
    const float* W;
    int sl, NT, mode, Klim;
    if (slot < 16)       { dst = WfF; W = Wf; sl = slot;       NT = 8;  mode = 0; Klim = 39;  }
    else if (slot < 112) { dst = W1F; W = W1; sl = slot - 16;  NT = 8;  mode = 0; Klim = 384; }
    else if (slot < 144) { dst = W2F; W = W2; sl = slot - 112; NT = 8;  mode = 0; Klim = 128; }
    else if (slot < 304) { dst = WLF; W = WL; sl = slot - 144; NT = 16; mode = 1; Klim = 0;   }
    else                 { dst = WRF; W = WR; sl = slot - 304; NT = 16; mode = 1; Klim = 0;   }

    int ks = sl / NT;
    int n = (sl - ks * NT) * 16 + l15;
    int kb = ks * 32 + lkk * 8;
    unsigned short* o = dst + ((size_t)sl * 64 + lane) * 8;
    #pragma unroll
    for (int j = 0; j < 8; ++j) {
        int k = kb + j;
        float v;
        if (mode == 0) {
            v = (k < Klim) ? W[(size_t)k * 128 + n] : 0.0f;
        } else {
            if (k < 256)      v = W[(size_t)(39 + k) * 256 + n];
            else if (k < 295) v = W[(size_t)(k - 256) * 256 + n];
            else              v = 0.0f;
        }
        o[j] = f2bf(v);
    }
}

// ---------------------------------------------------------------------------
// Fused main: Bresenham-interleaved atom / gather blocks, 4 blocks/CU.
// Atom path: K=32 chunk rhythm with issue-order-correct counted vmcnt —
// no global load inside a phase ever forces an async chunk to drain early.
// ---------------------------------------------------------------------------
__global__ __launch_bounds__(256, 4) void fused_main(
    const float* __restrict__ af, const float* __restrict__ am,
    const unsigned short* __restrict__ WfF, const float* __restrict__ bfe,
    const unsigned short* __restrict__ W1F, const float* __restrict__ b1,
    const unsigned short* __restrict__ W2F, const float* __restrict__ b2,
    const unsigned short* __restrict__ WLF, const float* __restrict__ bL,
    const unsigned short* __restrict__ WRF, const float* __restrict__ bR,
    const int* __restrict__ seg, const int* __restrict__ leaf_idx,
    const int* __restrict__ ring_idx, const int* __restrict__ rseg,
    float* __restrict__ out_mol, int* __restrict__ counts,
    float* __restrict__ out_leaf, float* __restrict__ out_ring,
    int N, int NL, int NRE, int nLeafBlocks, int NG, int T)
{
    __shared__ alignas(16) unsigned char Ebuf[16384];   // E tile, then H tile
    __shared__ alignas(16) unsigned char Mbuf[16384];   // 2x8KB chunks, then O
    __shared__ int sseg[64];

    const int t = threadIdx.x, lane = t & 63, w = t >> 6;
    const int lrow = lane & 15, lk = lane >> 4;

    const unsigned long long bid = blockIdx.x;
    const int g_before = (int)(bid * (unsigned long long)NG / (unsigned long long)T);
    const int g_after  = (int)((bid + 1ull) * (unsigned long long)NG / (unsigned long long)T);
    const bool is_gather = (g_after > g_before);

    if (!is_gather) {
        // ================= ATOM PATH =================
        const int ablk = (int)bid - g_before;
        const int r0 = ablk * 64;
        const int wr = w >> 1, wc = w & 1;
        unsigned char* M0 = Mbuf;
        unsigned char* M1 = Mbuf + 8192;

        // stage one K=32 chunk (8KB) of msg, source XOR-pre-swizzled
        auto stage8 = [&](unsigned char* buf, int cc) {
            #pragma unroll
            for (int p = 0; p < 2; ++p) {
                int i = t + p * 256;
                int r = i >> 3, sgl = i & 7;
                const float* src = am + ((size_t)min(r0 + r, N - 1) << 8)
                                      + cc * 32 + ((sgl ^ (r & 7)) << 2);
                async16(buf + (size_t)(p * 256 + w * 64) * 16, src);
            }
        };
        // load 4 weight B-frags (one k-step, this wave's col-half)
        auto ldwb = [&](bf16x8* dst, const unsigned short* WB, int ks) {
            const bf16x8* Wp = (const bf16x8*)WB + ((size_t)ks * 8 + wc * 4) * 64 + lane;
            #pragma unroll
            for (int nt = 0; nt < 4; ++nt) dst[nt] = Wp[nt * 64];
        };
        // one K=32 step from a msg chunk buffer
        auto cchunk = [&](const unsigned char* buf, const bf16x8* wbv, f32x4 (&acc)[2][4]) {
            #pragma unroll
            for (int mt = 0; mt < 2; ++mt) {
                int row = wr * 32 + mt * 16 + lrow;
                int s0 = (lk * 2) ^ (row & 7), s1 = (lk * 2 + 1) ^ (row & 7);
                float4 x0 = *(const float4*)(buf + row * 128 + (s0 << 4));
                float4 x1 = *(const float4*)(buf + row * 128 + (s1 << 4));
                bf16x8 a = cvt8(x0, x1);
                #pragma unroll
                for (int nt = 0; nt < 4; ++nt) acc[mt][nt] = mfma16(a, wbv[nt], acc[mt][nt]);
            }
        };
        // one K=32 step from a bf16 swizzled tile (E or H)
        auto tstep = [&](const unsigned char* buf, int ks, const bf16x8* wbv, f32x4 (&acc)[2][4]) {
            #pragma unroll
            for (int mt = 0; mt < 2; ++mt) {
                int row = wr * 32 + mt * 16 + lrow;
                int sg = (ks * 4 + lk) ^ (row & 15);
                bf16x8 a = *(const bf16x8*)(buf + row * 256 + (sg << 4));
                #pragma unroll
                for (int nt = 0; nt < 4; ++nt) acc[mt][nt] = mfma16(a, wbv[nt], acc[mt][nt]);
            }
        };
        auto tile_write = [&](unsigned char* buf, int row, int c, float v) {
            int byte = row * 256 + ((((c >> 3) ^ (row & 15))) << 4) + (c & 7) * 2;
            *(unsigned short*)(buf + byte) = f2bf(v);
        };

        // ---- prologue VMEM (oldest first): af, wf, biases, wbE0, c0, c1 ----
        int rowg0 = min(r0 + wr * 32 + lrow, N - 1);
        int rowg1 = min(r0 + wr * 32 + 16 + lrow, N - 1);
        float av0[2][8], av1[2][8];
        #pragma unroll
        for (int ks = 0; ks < 2; ++ks)
            #pragma unroll
            for (int j = 0; j < 8; ++j) {
                int k = ks * 32 + lk * 8 + j;
                av0[ks][j] = (k < 39) ? af[(size_t)rowg0 * 39 + k] : 0.f;
                av1[ks][j] = (k < 39) ? af[(size_t)rowg1 * 39 + k] : 0.f;
            }
        bf16x8 wf[2][4];
        ldwb(wf[0], WfF, 0);
        ldwb(wf[1], WfF, 1);
        float bfe_r[4], b1_r[4], b2_r[4];
        #pragma unroll
        for (int nt = 0; nt < 4; ++nt) {
            int c = wc * 64 + nt * 16 + lrow;
            bfe_r[nt] = bfe[c]; b1_r[nt] = b1[c]; b2_r[nt] = b2[c];
        }
        if (t < 64) sseg[t] = (r0 + t < N) ? seg[r0 + t] : -1;
        SBAR0;
        bf16x8 wbA[4], wbB[4];
        ldwb(wbA, W1F, 0);           // E-part step-0 weights
        SBAR0;
        stage8(M0, 0);
        stage8(M1, 1);
        SBAR0;

        // ---- phase 1: E = relu(af @ Wf + bf) -> Ebuf ----
        {
            f32x4 acc1[2][4] = {};
            #pragma unroll
            for (int ks = 0; ks < 2; ++ks) {
                bf16x8 a0 = cvt8s(av0[ks]);
                bf16x8 a1 = cvt8s(av1[ks]);
                #pragma unroll
                for (int nt = 0; nt < 4; ++nt) {
                    acc1[0][nt] = mfma16(a0, wf[ks][nt], acc1[0][nt]);
                    acc1[1][nt] = mfma16(a1, wf[ks][nt], acc1[1][nt]);
                }
            }
            #pragma unroll
            for (int nt = 0; nt < 4; ++nt) {
                int c = wc * 64 + nt * 16 + lrow;
                #pragma unroll
                for (int mt = 0; mt < 2; ++mt)
                    #pragma unroll
                    for (int rr = 0; rr < 4; ++rr) {
                        int row = wr * 32 + mt * 16 + lk * 4 + rr;
                        tile_write(Ebuf, row, c, fmaxf(acc1[mt][nt][rr] + bfe_r[nt], 0.f));
                    }
            }
        }
        BARX(8);   // E visible; wbA(4)+c0(2)+c1(2) stay in flight

        // ---- phase 2: H = relu([E | msg] @ W1 + b1) ----
        f32x4 acc2[2][4] = {};
        // E-part: 4 k-steps, rolling weight prefetch
        ldwb(wbB, W1F, 1); SBAR0; tstep(Ebuf, 0, wbA, acc2);
        ldwb(wbA, W1F, 2); SBAR0; tstep(Ebuf, 1, wbB, acc2);   // retires c0,c1
        ldwb(wbB, W1F, 3); SBAR0; tstep(Ebuf, 2, wbA, acc2);
        ldwb(wbA, W1F, 4); SBAR0; tstep(Ebuf, 3, wbB, acc2);   // wbA = c0 weights
        BARX(4);   // all waves past their c0/c1 retirement point

        // msg chunks c0..c7: {cc(c_i) w/ prefetch of w_{i+1}} ; BAR ; stage c_{i+2}
        ldwb(wbB, W1F, 5);  SBAR0; cchunk(M0, wbA, acc2);
        BARX(4); stage8(M0, 2); SBAR0;
        ldwb(wbA, W1F, 6);  SBAR0; cchunk(M1, wbB, acc2);
        BARX(4); stage8(M1, 3); SBAR0;
        ldwb(wbB, W1F, 7);  SBAR0; cchunk(M0, wbA, acc2);
        BARX(4); stage8(M0, 4); SBAR0;
        ldwb(wbA, W1F, 8);  SBAR0; cchunk(M1, wbB, acc2);
        BARX(4); stage8(M1, 5); SBAR0;
        ldwb(wbB, W1F, 9);  SBAR0; cchunk(M0, wbA, acc2);
        BARX(4); stage8(M0, 6); SBAR0;
        ldwb(wbA, W1F, 10); SBAR0; cchunk(M1, wbB, acc2);
        BARX(4); stage8(M1, 7); SBAR0;
        ldwb(wbB, W1F, 11); SBAR0; cchunk(M0, wbA, acc2);
        BARX(4);
        ldwb(wbA, W2F, 0);  SBAR0; cchunk(M1, wbB, acc2);      // c7; prefetch P3 ks0

        // ---- H epilogue -> Ebuf (E long dead) ----
        #pragma unroll
        for (int nt = 0; nt < 4; ++nt) {
            int c = wc * 64 + nt * 16 + lrow;
            #pragma unroll
            for (int mt = 0; mt < 2; ++mt)
                #pragma unroll
                for (int rr = 0; rr < 4; ++rr) {
                    int row = wr * 32 + mt * 16 + lk * 4 + rr;
                    tile_write(Ebuf, row, c, fmaxf(acc2[mt][nt][rr] + b1_r[nt], 0.f));
                }
        }
        BARX(4);   // H visible; W2F ks0 frags stay in flight

        // ---- phase 3: O = tanh(H @ W2 + b2) -> Mbuf overlay ----
        {
            f32x4 acc3[2][4] = {};
            ldwb(wbB, W2F, 1); SBAR0; tstep(Ebuf, 0, wbA, acc3);
            ldwb(wbA, W2F, 2); SBAR0; tstep(Ebuf, 1, wbB, acc3);
            ldwb(wbB, W2F, 3); SBAR0; tstep(Ebuf, 2, wbA, acc3);
            tstep(Ebuf, 3, wbB, acc3);
            #pragma unroll
            for (int nt = 0; nt < 4; ++nt) {
                int c = wc * 64 + nt * 16 + lrow;
                #pragma unroll
                for (int mt = 0; mt < 2; ++mt)
                    #pragma unroll
                    for (int rr = 0; rr < 4; ++rr) {
                        int row = wr * 32 + mt * 16 + lk * 4 + rr;
                        tile_write(Mbuf, row, c, fast_tanh(acc3[mt][nt][rr] + b2_r[nt]));
                    }
            }
        }
        asm volatile("s_waitcnt lgkmcnt(0)" ::: "memory");
        SBAR0;

        // ---- pooling: wave pools its own 32-row x 64-col quadrant of O ----
        {
            const int c = wc * 64 + lane;
            int cur = -1, runlen = 0;
            float s = 0.f, m = 0.f;
            #pragma unroll 1
            for (int a2 = 0; a2 < 32; ++a2) {
                int arow = wr * 32 + a2;
                int sg = sseg[arow];
                if (sg < 0) break;
                int byte = arow * 256 + ((((c >> 3) ^ (arow & 15))) << 4) + (c & 7) * 2;
                float v = bf2f(*(const unsigned short*)(Mbuf + byte));
                if (sg != cur) {
                    if (cur >= 0) {
                        atomicAdd(&out_mol[(size_t)cur * 256 + c], s);
                        atomicMax((unsigned int*)&out_mol[(size_t)cur * 256 + 128 + c],
                                  __float_as_uint(m + 2.0f));
                        if (wc == 0 && lane == 0) atomicAdd(&counts[cur], runlen);
                    }
                    cur = sg; s = v; m = v; runlen = 1;
                } else {
                    s += v; m = fmaxf(m, v); ++runlen;
                }
            }
            if (cur >= 0) {
                atomicAdd(&out_mol[(size_t)cur * 256 + c], s);
                atomicMax((unsigned int*)&out_mol[(size_t)cur * 256 + 128 + c],
                          __float_as_uint(m + 2.0f));
                if (wc == 0 && lane == 0) atomicAdd(&counts[cur], runlen);
            }
        }
        return;
    }

    // ================= GATHER PATH (leaf / ring) =================
    {
        const int gblk = g_before;
        const bool ring = gblk >= nLeafBlocks;
        const unsigned short* WF = ring ? WRF : WLF;
        const float* bv = ring ? bR : bL;
        const int* idx = ring ? ring_idx : leaf_idx;
        const int NROWS = ring ? NRE : NL;
        const int blk = ring ? gblk - nLeafBlocks : gblk;

        const int r0 = blk * 64 + (w & 1) * 32;
        const int colblk = w >> 1;
        const int i0 = idx[min(r0 + lrow, NROWS - 1)];
        const int i1 = idx[min(r0 + 16 + lrow, NROWS - 1)];

        f32x4 acc[2][8] = {};
        #pragma unroll
        for (int ks = 0; ks < 8; ++ks) {
            int k0 = ks * 32 + lk * 8;
            const float* p0 = am + ((size_t)i0 << 8) + k0;
            const float* p1 = am + ((size_t)i1 << 8) + k0;
            bf16x8 a0 = cvt8(*(const float4*)p0, *(const float4*)(p0 + 4));
            bf16x8 a1 = cvt8(*(const float4*)p1, *(const float4*)(p1 + 4));
            const bf16x8* B = (const bf16x8*)WF + (ks * 16 + colblk * 8) * 64 + lane;
            #pragma unroll
            for (int nt = 0; nt < 8; ++nt) {
                bf16x8 b = B[nt * 64];
                acc[0][nt] = mfma16(a0, b, acc[0][nt]);
                acc[1][nt] = mfma16(a1, b, acc[1][nt]);
            }
        }
        #pragma unroll
        for (int ks = 8; ks < 10; ++ks) {
            bf16x8 a0, a1;
            #pragma unroll
            for (int j = 0; j < 8; ++j) {
                int k = ks * 32 + lk * 8 + j - 256;
                float v0 = (k < 39) ? af[(size_t)i0 * 39 + k] : 0.0f;
                float v1 = (k < 39) ? af[(size_t)i1 * 39 + k] : 0.0f;
                a0[j] = (short)f2bf(v0); a1[j] = (short)f2bf(v1);
            }
            const bf16x8* B = (const bf16x8*)WF + (ks * 16 + colblk * 8) * 64 + lane;
            #pragma unroll
            for (int nt = 0; nt < 8; ++nt) {
                bf16x8 b = B[nt * 64];
                acc[0][nt] = mfma16(a0, b, acc[0][nt]);
                acc[1][nt] = mfma16(a1, b, acc[1][nt]);
            }
        }

        if (!ring) {
            #pragma unroll
            for (int nt = 0; nt < 8; ++nt) {
                int c = colblk * 128 + nt * 16 + lrow;
                float bias = bv[c];
                #pragma unroll
                for (int mt = 0; mt < 2; ++mt) {
                    #pragma unroll
                    for (int r = 0; r < 4; ++r) {
                        int row = r0 + mt * 16 + lk * 4 + r;
                        if (row < NROWS)
                            out_leaf[(size_t)row * 256 + c] = fast_tanh(acc[mt][nt][r] + bias);
                    }
                }
            }
        } else {
            int sg[2][4];
            #pragma unroll
            for (int mt = 0; mt < 2; ++mt)
                #pragma unroll
                for (int r = 0; r < 4; ++r) {
                    int rr = r0 + mt * 16 + lk * 4 + r;
                    sg[mt][r] = (rr < NROWS) ? rseg[rr] : -1;
                }
            #pragma unroll
            for (int nt = 0; nt < 8; ++nt) {
                int c = colblk * 128 + nt * 16 + lrow;
                float bias = bv[c];
                #pragma unroll
                for (int mt = 0; mt < 2; ++mt) {
                    int cur = -1; float accv = 0.0f;
                    #pragma unroll
                    for (int r = 0; r < 4; ++r) {
                        float v = fast_tanh(acc[mt][nt][r] + bias);
                        int s = sg[mt][r];
                        if (s != cur) {
                            if (cur >= 0) atomicAdd(&out_ring[(size_t)cur * 256 + c], accv);
                            cur = s; accv = v;
                        } else accv += v;
                    }
                    if (cur >= 0) atomicAdd(&out_ring[(size_t)cur * 256 + c], accv);
                }
            }
        }
    }
}

// ---------------------------------------------------------------------------
// Finalize molecule embedding in-place: avg = sum/count, max decode
// ---------------------------------------------------------------------------
__global__ void finalize_kernel(float* __restrict__ out, const int* __restrict__ counts, int M)
{
    int tid = blockIdx.x * blockDim.x + threadIdx.x;
    if (tid >= M * 128) return;
    int m = tid >> 7, c = tid & 127;
    int cnt = counts[m];
    float denom = (cnt > 0) ? (float)cnt : 1.0f;
    float s  = out[(size_t)m * 256 + c];
    float mr = out[(size_t)m * 256 + 128 + c];
    out[(size_t)m * 256 + c] = s / denom;
    out[(size_t)m * 256 + 128 + c] = (cnt > 0) ? (mr - 2.0f) : 0.0f;
}

extern "C" void kernel_launch(void* const* d_in, const int* in_sizes, int n_in,
                              void* d_out, int out_size, void* d_ws, size_t ws_size,
                              hipStream_t stream) {
    const float* af = (const float*)d_in[0];
    const float* am = (const float*)d_in[1];
    const float* Wf = (const float*)d_in[2];
    const float* bfe = (const float*)d_in[3];
    const float* W1 = (const float*)d_in[4];
    const float* b1 = (const float*)d_in[5];
    const float* W2 = (const float*)d_in[6];
    const float* b2 = (const float*)d_in[7];
    const float* WL = (const float*)d_in[8];
    const float* bL = (const float*)d_in[9];
    const float* WR = (const float*)d_in[10];
    const float* bR = (const float*)d_in[11];
    const int* seg      = (const int*)d_in[12];
    const int* leaf_idx = (const int*)d_in[13];
    const int* ring_idx = (const int*)d_in[14];
    const int* ring_seg = (const int*)d_in[15];

    const int N   = in_sizes[0] / 39;   // 300000
    const int NL  = in_sizes[13];       // 50000
    const int NRE = in_sizes[14];       // 120000
    const int M   = 10000;
    const int NR  = 20000;

    float* out = (float*)d_out;
    float* out_mol  = out;
    float* out_leaf = out + (size_t)M * 256;
    float* out_ring = out + (size_t)M * 256 + (size_t)NL * 256;

    // ws layout (16B-aligned offsets)
    int* counts = (int*)d_ws;                                       // 40 KB
    unsigned short* WfF = (unsigned short*)((char*)d_ws + 40960);   // 16 KB
    unsigned short* W1F = (unsigned short*)((char*)d_ws + 57344);   // 96 KB
    unsigned short* W2F = (unsigned short*)((char*)d_ws + 155648);  // 32 KB
    unsigned short* WLF = (unsigned short*)((char*)d_ws + 188416);  // 160 KB
    unsigned short* WRF = (unsigned short*)((char*)d_ws + 352256);  // 160 KB

    hipMemsetAsync(out_mol, 0, (size_t)M * 256 * sizeof(float), stream);
    hipMemsetAsync(out_ring, 0, (size_t)NR * 256 * sizeof(float), stream);
    hipMemsetAsync(counts, 0, (size_t)M * sizeof(int), stream);

    prep_frag<<<(29696 + 255) / 256, 256, 0, stream>>>(
        Wf, W1, W2, WL, WR, WfF, W1F, W2F, WLF, WRF);

    const int NA = (N + 63) / 64;
    const int nLeafBlocks = (NL + 63) / 64;
    const int nRingBlocks = (NRE + 63) / 64;
    const int NG = nLeafBlocks + nRingBlocks;
    const int T  = NA + NG;

    fused_main<<<T, 256, 0, stream>>>(
        af, am, WfF, bfe, W1F, b1, W2F, b2, WLF, bL, WRF, bR,
        seg, leaf_idx, ring_idx, ring_seg,
        out_mol, counts, out_leaf, out_ring,
        N, NL, NRE, nLeafBlocks, NG, T);

    finalize_kernel<<<(M * 128 + 255) / 256, 256, 0, stream>>>(out_mol, counts, M);
}

// Round 11
// 241.983 us; speedup vs baseline: 1.4427x; 1.2591x over previous
//
#include <hip/hip_runtime.h>
#include <math.h>

typedef __attribute__((ext_vector_type(8))) short bf16x8;
typedef __attribute__((ext_vector_type(4))) float f32x4;

__device__ __forceinline__ unsigned short f2bf(float x) {
    unsigned int u = __float_as_uint(x);
    u += 0x7fff + ((u >> 16) & 1);           // RNE
    return (unsigned short)(u >> 16);
}
__device__ __forceinline__ float bf2f(unsigned short b) {
    return __uint_as_float(((unsigned int)b) << 16);
}
__device__ __forceinline__ unsigned int cvtpk(float a, float b) {
    unsigned int r;
    asm("v_cvt_pk_bf16_f32 %0, %1, %2" : "=v"(r) : "v"(a), "v"(b));
    return r;
}
__device__ __forceinline__ float fast_tanh(float x) {
    float e = __expf(2.0f * x);
    return 1.0f - 2.0f / (e + 1.0f);
}
__device__ __forceinline__ f32x4 mfma16(bf16x8 a, bf16x8 b, f32x4 c) {
    return __builtin_amdgcn_mfma_f32_16x16x32_bf16(a, b, c, 0, 0, 0);
}
union bfu { unsigned int w[4]; bf16x8 v; };
__device__ __forceinline__ bf16x8 cvt8(float4 u, float4 v) {
    bfu x;
    x.w[0] = cvtpk(u.x, u.y); x.w[1] = cvtpk(u.z, u.w);
    x.w[2] = cvtpk(v.x, v.y); x.w[3] = cvtpk(v.z, v.w);
    return x.v;
}
__device__ __forceinline__ void async16(void* lds, const void* g) {
    __builtin_amdgcn_global_load_lds(
        (const __attribute__((address_space(1))) unsigned int*)g,
        (__attribute__((address_space(3))) unsigned int*)lds, 16, 0, 0);
}

#define SBAR0 __builtin_amdgcn_sched_barrier(0)
#define BARX(vm) do { SBAR0; \
    asm volatile("s_waitcnt vmcnt(" #vm ") lgkmcnt(0)" ::: "memory"); \
    __builtin_amdgcn_s_barrier(); SBAR0; } while (0)

// ---------------------------------------------------------------------------
// Prep: weights -> frag-major bf16 (default k-map; R4 layout).
// ---------------------------------------------------------------------------
__global__ void prep_frag(const float* __restrict__ Wf, const float* __restrict__ W1,
                          const float* __restrict__ W2, const float* __restrict__ WL,
                          const float* __restrict__ WR,
                          unsigned short* __restrict__ WfF, unsigned short* __restrict__ W1F,
                          unsigned short* __restrict__ W2F, unsigned short* __restrict__ WLF,
                          unsigned short* __restrict__ WRF)
{
    int g = blockIdx.x * 256 + threadIdx.x;
    if (g >= 29696) return;
    int lane = g & 63, slot = g >> 6;
    int l15 = lane & 15, lkk = lane >> 4;

    unsigned short* dst;
    const float* W;
    int sl, NT, mode, Klim;
    if (slot < 16)       { dst = WfF; W = Wf; sl = slot;       NT = 8;  mode = 0; Klim = 39;  }
    else if (slot < 112) { dst = W1F; W = W1; sl = slot - 16;  NT = 8;  mode = 0; Klim = 384; }
    else if (slot < 144) { dst = W2F; W = W2; sl = slot - 112; NT = 8;  mode = 0; Klim = 128; }
    else if (slot < 304) { dst = WLF; W = WL; sl = slot - 144; NT = 16; mode = 1; Klim = 0;   }
    else                 { dst = WRF; W = WR; sl = slot - 304; NT = 16; mode = 1; Klim = 0;   }

    int ks = sl / NT;
    int n = (sl - ks * NT) * 16 + l15;
    int kb = ks * 32 + lkk * 8;
    unsigned short* o = dst + ((size_t)sl * 64 + lane) * 8;
    #pragma unroll
    for (int j = 0; j < 8; ++j) {
        int k = kb + j;
        float v;
        if (mode == 0) {
            v = (k < Klim) ? W[(size_t)k * 128 + n] : 0.0f;
        } else {
            if (k < 256)      v = W[(size_t)(39 + k) * 256 + n];
            else if (k < 295) v = W[(size_t)(k - 256) * 256 + n];
            else              v = 0.0f;
        }
        o[j] = f2bf(v);
    }
}

// ---------------------------------------------------------------------------
// Fused main: Bresenham-interleaved atom / gather blocks, 4 blocks/CU.
// ALL A-operand global reads are row-contiguous (no 16-scattered-line instrs):
//   atom: af staged as one contiguous block; msg via global_load_lds.
//   gather: msg+af rows staged to LDS with per-row coalesced loads.
// ---------------------------------------------------------------------------
__global__ __launch_bounds__(256, 4) void fused_main(
    const float* __restrict__ af, const float* __restrict__ am,
    const unsigned short* __restrict__ WfF, const float* __restrict__ bfe,
    const unsigned short* __restrict__ W1F, const float* __restrict__ b1,
    const unsigned short* __restrict__ W2F, const float* __restrict__ b2,
    const unsigned short* __restrict__ WLF, const float* __restrict__ bL,
    const unsigned short* __restrict__ WRF, const float* __restrict__ bR,
    const int* __restrict__ seg, const int* __restrict__ leaf_idx,
    const int* __restrict__ ring_idx, const int* __restrict__ rseg,
    float* __restrict__ out_mol, int* __restrict__ counts,
    float* __restrict__ out_leaf, float* __restrict__ out_ring,
    int N, int NL, int NRE, int nLeafBlocks, int NG, int T)
{
    __shared__ alignas(16) unsigned char LDSb[32768];   // atom: Ebuf|Mbuf; gather: X tile
    __shared__ alignas(16) unsigned short Fb[2688];     // af tile [64][40] + pads
    __shared__ int sseg[64];

    const int t = threadIdx.x, lane = t & 63, w = t >> 6;
    const int lrow = lane & 15, lk = lane >> 4;

    const unsigned long long bid = blockIdx.x;
    const int g_before = (int)(bid * (unsigned long long)NG / (unsigned long long)T);
    const int g_after  = (int)((bid + 1ull) * (unsigned long long)NG / (unsigned long long)T);
    const bool is_gather = (g_after > g_before);

    if (!is_gather) {
        // ================= ATOM PATH =================
        const int ablk = (int)bid - g_before;
        const int r0 = ablk * 64;
        const int wr = w >> 1, wc = w & 1;
        unsigned char* Ebuf = LDSb;            // E tile, then H tile
        unsigned char* Mbuf = LDSb + 16384;    // 2x8KB chunks, then O
        unsigned char* M0 = Mbuf;
        unsigned char* M1 = Mbuf + 8192;

        auto stage8 = [&](unsigned char* buf, int cc) {
            #pragma unroll
            for (int p = 0; p < 2; ++p) {
                int i = t + p * 256;
                int r = i >> 3, sgl = i & 7;
                const float* src = am + ((size_t)min(r0 + r, N - 1) << 8)
                                      + cc * 32 + ((sgl ^ (r & 7)) << 2);
                async16(buf + (size_t)(p * 256 + w * 64) * 16, src);
            }
        };
        auto ldwb = [&](bf16x8* dst, const unsigned short* WB, int ks) {
            const bf16x8* Wp = (const bf16x8*)WB + ((size_t)ks * 8 + wc * 4) * 64 + lane;
            #pragma unroll
            for (int nt = 0; nt < 4; ++nt) dst[nt] = Wp[nt * 64];
        };
        auto cchunk = [&](const unsigned char* buf, const bf16x8* wbv, f32x4 (&acc)[2][4]) {
            #pragma unroll
            for (int mt = 0; mt < 2; ++mt) {
                int row = wr * 32 + mt * 16 + lrow;
                int s0 = (lk * 2) ^ (row & 7), s1 = (lk * 2 + 1) ^ (row & 7);
                float4 x0 = *(const float4*)(buf + row * 128 + (s0 << 4));
                float4 x1 = *(const float4*)(buf + row * 128 + (s1 << 4));
                bf16x8 a = cvt8(x0, x1);
                #pragma unroll
                for (int nt = 0; nt < 4; ++nt) acc[mt][nt] = mfma16(a, wbv[nt], acc[mt][nt]);
            }
        };
        auto tstep = [&](const unsigned char* buf, int ks, const bf16x8* wbv, f32x4 (&acc)[2][4]) {
            #pragma unroll
            for (int mt = 0; mt < 2; ++mt) {
                int row = wr * 32 + mt * 16 + lrow;
                int sg = (ks * 4 + lk) ^ (row & 15);
                bf16x8 a = *(const bf16x8*)(buf + row * 256 + (sg << 4));
                #pragma unroll
                for (int nt = 0; nt < 4; ++nt) acc[mt][nt] = mfma16(a, wbv[nt], acc[mt][nt]);
            }
        };
        auto tile_write = [&](unsigned char* buf, int row, int c, float v) {
            int byte = row * 256 + ((((c >> 3) ^ (row & 15))) << 4) + (c & 7) * 2;
            *(unsigned short*)(buf + byte) = f2bf(v);
        };

        // ---- prologue: contiguous af block load (oldest VMEM), weights, seg ----
        float afv[10];
        #pragma unroll
        for (int p = 0; p < 10; ++p) {
            int i = t + p * 256;
            size_t g = (size_t)r0 * 39 + i;
            afv[p] = (i < 2496 && g < (size_t)N * 39) ? af[g] : 0.f;
        }
        bf16x8 wf[2][4];
        ldwb(wf[0], WfF, 0);
        ldwb(wf[1], WfF, 1);
        float bfe_r[4], b1_r[4], b2_r[4];
        #pragma unroll
        for (int nt = 0; nt < 4; ++nt) {
            int c = wc * 64 + nt * 16 + lrow;
            bfe_r[nt] = bfe[c]; b1_r[nt] = b1[c]; b2_r[nt] = b2[c];
        }
        if (t < 64) sseg[t] = (r0 + t < N) ? seg[r0 + t] : -1;
        bf16x8 wbA[4], wbB[4];
        ldwb(wbA, W1F, 0);
        SBAR0;
        stage8(M0, 0);                 // newest VMEM: 4 asyncs stay in flight
        stage8(M1, 1);
        SBAR0;
        // write af tile (forces af retirements; asyncs are newer -> unaffected)
        #pragma unroll
        for (int p = 0; p < 10; ++p) {
            int i = t + p * 256;
            if (i < 2496) { int rf = i / 39, kf = i - rf * 39; Fb[rf * 40 + kf] = f2bf(afv[p]); }
        }
        if (t < 64) Fb[t * 40 + 39] = 0;
        if (t < 128) Fb[2560 + t] = 0;
        BARX(4);   // Fb visible; c0,c1 in flight

        // ---- phase 1: E = relu(af @ Wf + bf) -> Ebuf (A-frags from Fb) ----
        {
            f32x4 acc1[2][4] = {};
            #pragma unroll
            for (int ks = 0; ks < 2; ++ks) {
                bf16x8 a0 = *(const bf16x8*)((const unsigned char*)Fb
                              + (wr * 32 + lrow) * 80 + ks * 64 + lk * 16);
                bf16x8 a1 = *(const bf16x8*)((const unsigned char*)Fb
                              + (wr * 32 + 16 + lrow) * 80 + ks * 64 + lk * 16);
                #pragma unroll
                for (int nt = 0; nt < 4; ++nt) {
                    acc1[0][nt] = mfma16(a0, wf[ks][nt], acc1[0][nt]);
                    acc1[1][nt] = mfma16(a1, wf[ks][nt], acc1[1][nt]);
                }
            }
            #pragma unroll
            for (int nt = 0; nt < 4; ++nt) {
                int c = wc * 64 + nt * 16 + lrow;
                #pragma unroll
                for (int mt = 0; mt < 2; ++mt)
                    #pragma unroll
                    for (int rr = 0; rr < 4; ++rr) {
                        int row = wr * 32 + mt * 16 + lk * 4 + rr;
                        tile_write(Ebuf, row, c, fmaxf(acc1[mt][nt][rr] + bfe_r[nt], 0.f));
                    }
            }
        }
        BARX(4);   // E visible; c0,c1 still in flight

        // ---- phase 2: H = relu([E | msg] @ W1 + b1) ----
        f32x4 acc2[2][4] = {};
        ldwb(wbB, W1F, 1); SBAR0; tstep(Ebuf, 0, wbA, acc2);
        ldwb(wbA, W1F, 2); SBAR0; tstep(Ebuf, 1, wbB, acc2);
        ldwb(wbB, W1F, 3); SBAR0; tstep(Ebuf, 2, wbA, acc2);
        ldwb(wbA, W1F, 4); SBAR0; tstep(Ebuf, 3, wbB, acc2);
        BARX(4);

        ldwb(wbB, W1F, 5);  SBAR0; cchunk(M0, wbA, acc2);
        BARX(4); stage8(M0, 2); SBAR0;
        ldwb(wbA, W1F, 6);  SBAR0; cchunk(M1, wbB, acc2);
        BARX(4); stage8(M1, 3); SBAR0;
        ldwb(wbB, W1F, 7);  SBAR0; cchunk(M0, wbA, acc2);
        BARX(4); stage8(M0, 4); SBAR0;
        ldwb(wbA, W1F, 8);  SBAR0; cchunk(M1, wbB, acc2);
        BARX(4); stage8(M1, 5); SBAR0;
        ldwb(wbB, W1F, 9);  SBAR0; cchunk(M0, wbA, acc2);
        BARX(4); stage8(M0, 6); SBAR0;
        ldwb(wbA, W1F, 10); SBAR0; cchunk(M1, wbB, acc2);
        BARX(4); stage8(M1, 7); SBAR0;
        ldwb(wbB, W1F, 11); SBAR0; cchunk(M0, wbA, acc2);
        BARX(4);
        ldwb(wbA, W2F, 0);  SBAR0; cchunk(M1, wbB, acc2);

        // ---- H epilogue -> Ebuf (E dead) ----
        #pragma unroll
        for (int nt = 0; nt < 4; ++nt) {
            int c = wc * 64 + nt * 16 + lrow;
            #pragma unroll
            for (int mt = 0; mt < 2; ++mt)
                #pragma unroll
                for (int rr = 0; rr < 4; ++rr) {
                    int row = wr * 32 + mt * 16 + lk * 4 + rr;
                    tile_write(Ebuf, row, c, fmaxf(acc2[mt][nt][rr] + b1_r[nt], 0.f));
                }
        }
        BARX(4);   // H visible; W2F ks0 frags in flight

        // ---- phase 3: O = tanh(H @ W2 + b2) -> Mbuf overlay ----
        {
            f32x4 acc3[2][4] = {};
            ldwb(wbB, W2F, 1); SBAR0; tstep(Ebuf, 0, wbA, acc3);
            ldwb(wbA, W2F, 2); SBAR0; tstep(Ebuf, 1, wbB, acc3);
            ldwb(wbB, W2F, 3); SBAR0; tstep(Ebuf, 2, wbA, acc3);
            tstep(Ebuf, 3, wbB, acc3);
            #pragma unroll
            for (int nt = 0; nt < 4; ++nt) {
                int c = wc * 64 + nt * 16 + lrow;
                #pragma unroll
                for (int mt = 0; mt < 2; ++mt)
                    #pragma unroll
                    for (int rr = 0; rr < 4; ++rr) {
                        int row = wr * 32 + mt * 16 + lk * 4 + rr;
                        tile_write(Mbuf, row, c, fast_tanh(acc3[mt][nt][rr] + b2_r[nt]));
                    }
            }
        }
        asm volatile("s_waitcnt lgkmcnt(0)" ::: "memory");
        SBAR0;

        // ---- pooling ----
        {
            const int c = wc * 64 + lane;
            int cur = -1, runlen = 0;
            float s = 0.f, m = 0.f;
            #pragma unroll 1
            for (int a2 = 0; a2 < 32; ++a2) {
                int arow = wr * 32 + a2;
                int sg = sseg[arow];
                if (sg < 0) break;
                int byte = arow * 256 + ((((c >> 3) ^ (arow & 15))) << 4) + (c & 7) * 2;
                float v = bf2f(*(const unsigned short*)(Mbuf + byte));
                if (sg != cur) {
                    if (cur >= 0) {
                        atomicAdd(&out_mol[(size_t)cur * 256 + c], s);
                        atomicMax((unsigned int*)&out_mol[(size_t)cur * 256 + 128 + c],
                                  __float_as_uint(m + 2.0f));
                        if (wc == 0 && lane == 0) atomicAdd(&counts[cur], runlen);
                    }
                    cur = sg; s = v; m = v; runlen = 1;
                } else {
                    s += v; m = fmaxf(m, v); ++runlen;
                }
            }
            if (cur >= 0) {
                atomicAdd(&out_mol[(size_t)cur * 256 + c], s);
                atomicMax((unsigned int*)&out_mol[(size_t)cur * 256 + 128 + c],
                          __float_as_uint(m + 2.0f));
                if (wc == 0 && lane == 0) atomicAdd(&counts[cur], runlen);
            }
        }
        return;
    }

    // ================= GATHER PATH (leaf / ring) =================
    {
        const int gblk = g_before;
        const bool ring = gblk >= nLeafBlocks;
        const unsigned short* WF = ring ? WRF : WLF;
        const float* bv = ring ? bR : bL;
        const int* idx = ring ? ring_idx : leaf_idx;
        const int NROWS = ring ? NRE : NL;
        const int blk = ring ? gblk - nLeafBlocks : gblk;
        const int r0 = blk * 64;
        const int wrg = w & 1, wcg = w >> 1;      // rows wrg*32, cols wcg*128

        if (t < 64) sseg[t] = idx[min(r0 + t, NROWS - 1)];
        __syncthreads();

        // ---- stage msg rows -> swizzled bf16 X tile (row-contiguous loads) ----
        unsigned char* Xb = LDSb;
        #pragma unroll
        for (int p = 0; p < 16; ++p) {
            int i = t + p * 256;
            int r = i >> 6, kq = i & 63;
            float4 v = *(const float4*)(am + ((size_t)sseg[r] << 8) + kq * 4);
            uint2 u;
            u.x = cvtpk(v.x, v.y); u.y = cvtpk(v.z, v.w);
            *(uint2*)(Xb + r * 512 + (((kq >> 1) ^ (r & 15)) << 4) + (kq & 1) * 8) = u;
        }
        // ---- stage af rows -> Fb tile ----
        #pragma unroll
        for (int p = 0; p < 10; ++p) {
            int i = t + p * 256;
            if (i < 2496) {
                int rf = i / 39, kf = i - rf * 39;
                Fb[rf * 40 + kf] = f2bf(af[(size_t)sseg[rf] * 39 + kf]);
            }
        }
        if (t < 64) Fb[t * 40 + 39] = 0;
        if (t < 128) Fb[2560 + t] = 0;
        __syncthreads();

        f32x4 acc[2][8] = {};
        #pragma unroll
        for (int ks = 0; ks < 8; ++ks) {          // msg K-part from LDS
            bf16x8 wb[8];
            const bf16x8* B = (const bf16x8*)WF + (ks * 16 + wcg * 8) * 64 + lane;
            #pragma unroll
            for (int nt = 0; nt < 8; ++nt) wb[nt] = B[nt * 64];
            #pragma unroll
            for (int mt = 0; mt < 2; ++mt) {
                int row = wrg * 32 + mt * 16 + lrow;
                bf16x8 a = *(const bf16x8*)(Xb + row * 512 + ((((ks * 4 + lk) ^ (row & 15))) << 4));
                #pragma unroll
                for (int nt = 0; nt < 8; ++nt) acc[mt][nt] = mfma16(a, wb[nt], acc[mt][nt]);
            }
        }
        #pragma unroll
        for (int ks = 8; ks < 10; ++ks) {         // af K-part from Fb
            bf16x8 wb[8];
            const bf16x8* B = (const bf16x8*)WF + (ks * 16 + wcg * 8) * 64 + lane;
            #pragma unroll
            for (int nt = 0; nt < 8; ++nt) wb[nt] = B[nt * 64];
            #pragma unroll
            for (int mt = 0; mt < 2; ++mt) {
                int row = wrg * 32 + mt * 16 + lrow;
                bf16x8 a = *(const bf16x8*)((const unsigned char*)Fb
                              + row * 80 + (ks - 8) * 64 + lk * 16);
                #pragma unroll
                for (int nt = 0; nt < 8; ++nt) acc[mt][nt] = mfma16(a, wb[nt], acc[mt][nt]);
            }
        }

        if (!ring) {
            #pragma unroll
            for (int nt = 0; nt < 8; ++nt) {
                int c = wcg * 128 + nt * 16 + lrow;
                float bias = bv[c];
                #pragma unroll
                for (int mt = 0; mt < 2; ++mt) {
                    #pragma unroll
                    for (int r = 0; r < 4; ++r) {
                        int row = r0 + wrg * 32 + mt * 16 + lk * 4 + r;
                        if (row < NROWS)
                            out_leaf[(size_t)row * 256 + c] = fast_tanh(acc[mt][nt][r] + bias);
                    }
                }
            }
        } else {
            int sg[2][4];
            #pragma unroll
            for (int mt = 0; mt < 2; ++mt)
                #pragma unroll
                for (int r = 0; r < 4; ++r) {
                    int rr = r0 + wrg * 32 + mt * 16 + lk * 4 + r;
                    sg[mt][r] = (rr < NROWS) ? rseg[rr] : -1;
                }
            #pragma unroll
            for (int nt = 0; nt < 8; ++nt) {
                int c = wcg * 128 + nt * 16 + lrow;
                float bias = bv[c];
                #pragma unroll
                for (int mt = 0; mt < 2; ++mt) {
                    int cur = -1; float accv = 0.0f;
                    #pragma unroll
                    for (int r = 0; r < 4; ++r) {
                        float v = fast_tanh(acc[mt][nt][r] + bias);
                        int s = sg[mt][r];
                        if (s != cur) {
                            if (cur >= 0) atomicAdd(&out_ring[(size_t)cur * 256 + c], accv);
                            cur = s; accv = v;
                        } else accv += v;
                    }
                    if (cur >= 0) atomicAdd(&out_ring[(size_t)cur * 256 + c], accv);
                }
            }
        }
    }
}

// ---------------------------------------------------------------------------
// Finalize molecule embedding in-place: avg = sum/count, max decode
// ---------------------------------------------------------------------------
__global__ void finalize_kernel(float* __restrict__ out, const int* __restrict__ counts, int M)
{
    int tid = blockIdx.x * blockDim.x + threadIdx.x;
    if (tid >= M * 128) return;
    int m = tid >> 7, c = tid & 127;
    int cnt = counts[m];
    float denom = (cnt > 0) ? (float)cnt : 1.0f;
    float s  = out[(size_t)m * 256 + c];
    float mr = out[(size_t)m * 256 + 128 + c];
    out[(size_t)m * 256 + c] = s / denom;
    out[(size_t)m * 256 + 128 + c] = (cnt > 0) ? (mr - 2.0f) : 0.0f;
}

extern "C" void kernel_launch(void* const* d_in, const int* in_sizes, int n_in,
                              void* d_out, int out_size, void* d_ws, size_t ws_size,
                              hipStream_t stream) {
    const float* af = (const float*)d_in[0];
    const float* am = (const float*)d_in[1];
    const float* Wf = (const float*)d_in[2];
    const float* bfe = (const float*)d_in[3];
    const float* W1 = (const float*)d_in[4];
    const float* b1 = (const float*)d_in[5];
    const float* W2 = (const float*)d_in[6];
    const float* b2 = (const float*)d_in[7];
    const float* WL = (const float*)d_in[8];
    const float* bL = (const float*)d_in[9];
    const float* WR = (const float*)d_in[10];
    const float* bR = (const float*)d_in[11];
    const int* seg      = (const int*)d_in[12];
    const int* leaf_idx = (const int*)d_in[13];
    const int* ring_idx = (const int*)d_in[14];
    const int* ring_seg = (const int*)d_in[15];

    const int N   = in_sizes[0] / 39;   // 300000
    const int NL  = in_sizes[13];       // 50000
    const int NRE = in_sizes[14];       // 120000
    const int M   = 10000;
    const int NR  = 20000;

    float* out = (float*)d_out;
    float* out_mol  = out;
    float* out_leaf = out + (size_t)M * 256;
    float* out_ring = out + (size_t)M * 256 + (size_t)NL * 256;

    // ws layout (16B-aligned offsets)
    int* counts = (int*)d_ws;                                       // 40 KB
    unsigned short* WfF = (unsigned short*)((char*)d_ws + 40960);   // 16 KB
    unsigned short* W1F = (unsigned short*)((char*)d_ws + 57344);   // 96 KB
    unsigned short* W2F = (unsigned short*)((char*)d_ws + 155648);  // 32 KB
    unsigned short* WLF = (unsigned short*)((char*)d_ws + 188416);  // 160 KB
    unsigned short* WRF = (unsigned short*)((char*)d_ws + 352256);  // 160 KB

    hipMemsetAsync(out_mol, 0, (size_t)M * 256 * sizeof(float), stream);
    hipMemsetAsync(out_ring, 0, (size_t)NR * 256 * sizeof(float), stream);
    hipMemsetAsync(counts, 0, (size_t)M * sizeof(int), stream);

    prep_frag<<<(29696 + 255) / 256, 256, 0, stream>>>(
        Wf, W1, W2, WL, WR, WfF, W1F, W2F, WLF, WRF);

    const int NA = (N + 63) / 64;
    const int nLeafBlocks = (NL + 63) / 64;
    const int nRingBlocks = (NRE + 63) / 64;
    const int NG = nLeafBlocks + nRingBlocks;
    const int T  = NA + NG;

    fused_main<<<T, 256, 0, stream>>>(
        af, am, WfF, bfe, W1F, b1, W2F, b2, WLF, bL, WRF, bR,
        seg, leaf_idx, ring_idx, ring_seg,
        out_mol, counts, out_leaf, out_ring,
        N, NL, NRE, nLeafBlocks, NG, T);

    finalize_kernel<<<(M * 128 + 255) / 256, 256, 0, stream>>>(out_mol, counts, M);
}